// Round 13
// baseline (76.777 us; speedup 1.0000x reference)
//
#include <hip/hip_runtime.h>

typedef _Float16 h2 __attribute__((ext_vector_type(2)));

__device__ __forceinline__ float fd2(unsigned a, unsigned b, float c) {
  return __builtin_amdgcn_fdot2(__builtin_bit_cast(h2, a), __builtin_bit_cast(h2, b), c, false);
}
__device__ __forceinline__ unsigned pkrtz(float a, float b) {
  return __builtin_bit_cast(unsigned, __builtin_amdgcn_cvt_pkrtz(a, b));
}

// LDS-only barrier: drains ds ops, leaves global loads/stores in flight.
__device__ __forceinline__ void wg_barrier_lds() {
  asm volatile("s_waitcnt lgkmcnt(0)\n\ts_barrier" ::: "memory");
}

#define TW 64
#define TH 32
#define ROWS 36   // TH + 4
#define SWW 84    // sHS row stride (words)
#define SLW 88    // sL  row stride (f16s)
#define NT 4      // tiles (stacked in y) per block

__global__ __launch_bounds__(256, 4) void fused_hsl_conv(
    const float* __restrict__ x,
    const float* __restrict__ w1,
    const float* __restrict__ b1,
    const float* __restrict__ w2,
    const float* __restrict__ b2,
    float* __restrict__ out,
    int B)
{
  // ---- phase skew: break the device-wide load/compute/store convoy ----
  // All blocks launch at t=0 with identical deterministic schedules, so HBM
  // alternates "all-load" / "all-compute(idle)" windows -> per-iter time =
  // mem + compute (sum). Skew classes stagger block start by ~4.5us steps
  // (quarter iteration) so memory demand is continuous (max, not sum).
  {
    const int skew = (blockIdx.x >> 8) & 3;   // blocks i, i+256 likely same CU
    #pragma unroll
    for (int i = 0; i < 6; ++i)
      if (i < 2 * skew) asm volatile("s_sleep 84");  // 84*64cyc ~ 2.24us each
  }

  __shared__ unsigned sHS[2][ROWS][SWW];
  __shared__ __align__(16) _Float16 sL[2][ROWS][SLW];
  __shared__ unsigned swHS[5][16];
  __shared__ unsigned swL[5][16];

  const int tid = threadIdx.x;

  // ---- weight staging ----
  if (tid < 15) {
    const int o = tid % 3, dy = tid / 3;
    #pragma unroll
    for (int dx = 0; dx < 5; ++dx)
      swHS[dy][o * 5 + dx] = pkrtz(w2[o * 50 + dy * 5 + dx],
                                   w2[o * 50 + 25 + dy * 5 + dx]);
  } else if (tid >= 32 && tid < 47) {
    const int t2 = tid - 32, o = t2 % 3, dy = t2 / 3;
    float wv[5];
    #pragma unroll
    for (int dx = 0; dx < 5; ++dx) wv[dx] = w1[o * 25 + dy * 5 + dx];
    swL[dy][o * 3 + 0] = pkrtz(wv[0], wv[1]);
    swL[dy][o * 3 + 1] = pkrtz(wv[2], wv[3]);
    swL[dy][o * 3 + 2] = pkrtz(wv[4], 0.f);
  } else if (tid >= 64 && tid < 69) {
    swHS[tid - 64][15] = 0;
  } else if (tid >= 96 && tid < 131) {
    const int t3 = tid - 96;
    swL[t3 / 7][9 + t3 % 7] = 0;
  }
  // zero sL pad words 34,35 of every row, BOTH buffers
  if (tid < 72) {
    const int r = tid >> 1, w = 34 + (tid & 1);
    ((unsigned*)&sL[0][r][0])[w] = 0;
    ((unsigned*)&sL[1][r][0])[w] = 0;
  }

  // ---- block -> (b, tx, ychunk) with bijective XCD swizzle ----
  const int nwg = gridDim.x;                      // B*32, %8==0
  const int bsw = (blockIdx.x & 7) * (nwg >> 3) + (blockIdx.x >> 3);
  const int b   = bsw >> 5;
  const int rem = bsw & 31;
  const int tx0 = (rem & 7) * TW;
  const int tyb = (rem >> 3) * (NT * TH);

  const size_t pln = 512 * 512;
  const float* pr = x + (size_t)b * 3 * pln;
  const float* pg = pr + pln;
  const float* pb = pg + pln;
  float* outl = out + (size_t)b * 3 * pln;
  float* outr = out + ((size_t)B + b) * 3 * pln;

  const float b1v0 = b1[0], b1v1 = b1[1], b1v2 = b1[2];
  const float b2v0 = b2[0], b2v1 = b2[1], b2v2 = b2[2];

  // staging geometry: 36 rows x 18 float4-groups = 648 = 3*216
  const bool act = tid < 216;
  int rowA[3], tA[3];
  #pragma unroll
  for (int k = 0; k < 3; ++k) {
    const int i = k * 216 + tid;
    rowA[k] = i / 18;
    tA[k]   = i - rowA[k] * 18;
  }

  auto issue_loads = [&](int ty0, float4* Rv, float4* Gv, float4* Bv) {
    #pragma unroll
    for (int k = 0; k < 3; ++k) {
      const int gy  = ty0 - 2 + rowA[k];
      const int gx0 = tx0 - 4 + 4 * tA[k];
      Rv[k] = make_float4(0.f, 0.f, 0.f, 0.f);
      Gv[k] = Rv[k]; Bv[k] = Rv[k];
      if (act && gy >= 0 && gy < 512 && gx0 >= 0 && gx0 < 512) {
        const size_t off = (size_t)gy * 512 + gx0;
        Rv[k] = *(const float4*)(pr + off);
        Gv[k] = *(const float4*)(pg + off);
        Bv[k] = *(const float4*)(pb + off);
      }
    }
  };

  auto convert_store = [&](int buf, const float4* Rv, const float4* Gv, const float4* Bv) {
    #pragma unroll
    for (int k = 0; k < 3; ++k) {
      const int row = rowA[k], t = tA[k];
      const float ra[4] = {Rv[k].x, Rv[k].y, Rv[k].z, Rv[k].w};
      const float ga[4] = {Gv[k].x, Gv[k].y, Gv[k].z, Gv[k].w};
      const float ba[4] = {Bv[k].x, Bv[k].y, Bv[k].z, Bv[k].w};
      unsigned hs[4]; _Float16 lv[4];
      #pragma unroll
      for (int p = 0; p < 4; ++p) {
        const float r = ra[p], g = ga[p], bl = ba[p];
        const float cmax = fmaxf(r, fmaxf(g, bl));
        const float cmin = fminf(r, fminf(g, bl));
        const float delta = cmax - cmin;
        const float l = 0.5f * (cmax + cmin);
        const float rd = __builtin_amdgcn_rcpf(delta);
        float h0 = (g - bl) * rd;
        h0 = (h0 < 0.f) ? h0 + 6.f : h0;
        const float h1v = (bl - r) * rd + 2.f;
        const float h2v = (r - g) * rd + 4.f;
        float hv = (r >= g && r >= bl) ? h0 : ((g >= bl) ? h1v : h2v);
        const float h = (delta != 0.f) ? hv * (1.f / 6.f) : 0.f;
        const float denom = (l <= 0.5f) ? (2.f * l) : (2.f - 2.f * l);
        const float s = (delta != 0.f && l > 0.f && l < 1.f)
                          ? delta * __builtin_amdgcn_rcpf(denom) : 0.f;
        hs[p] = pkrtz(h, s);
        lv[p] = (_Float16)l;
      }
      if (act) {
        if (t >= 1)  *(uint2*)&sHS[buf][row][4 * t - 2] = make_uint2(hs[0], hs[1]);
        if (t <= 16) *(uint2*)&sHS[buf][row][4 * t]     = make_uint2(hs[2], hs[3]);
        unsigned* rl = (unsigned*)&sL[buf][row][0];
        if (t >= 1)  rl[2 * t - 1] = __builtin_bit_cast(unsigned, (h2){lv[0], lv[1]});
        if (t <= 16) rl[2 * t]     = __builtin_bit_cast(unsigned, (h2){lv[2], lv[3]});
      }
    }
  };

  // conv ownership: lane owns TWO quads of one row: px 4lx..4lx+3 and 32+4lx..35+4lx.
  // Per store instruction: 8 lanes x 16B at 16B stride = 128B contiguous.
  const int lx = tid & 7;      // 0..7
  const int ly = tid >> 3;     // 0..31
  const int c0 = 4 * lx;       // quad A px base; quad B = c0 + 32

  // ---- prologue: tile 0 ----
  float4 Rv[3], Gv[3], Bv[3];
  issue_loads(tyb, Rv, Gv, Bv);
  convert_store(0, Rv, Gv, Bv);
  wg_barrier_lds();

  for (int it = 0; it < NT; ++it) {
    const int ty0 = tyb + it * TH;
    const int buf = it & 1;

    // issue next tile's loads; pin above compute
    float4 Rn[3], Gn[3], Bn[3];
    if (it + 1 < NT) issue_loads(ty0 + TH, Rn, Gn, Bn);
    __builtin_amdgcn_sched_barrier(0);

    const size_t ob = (size_t)(ty0 + ly) * 512 + (tx0 + c0);

    // pass 1: HS -> xr  (two quads; tap dx of px p uses word base+p+dx)
    {
      float acc[2][3][4];
      #pragma unroll
      for (int q = 0; q < 2; ++q)
        #pragma unroll
        for (int p = 0; p < 4; ++p) { acc[q][0][p] = b2v0; acc[q][1][p] = b2v1; acc[q][2][p] = b2v2; }
      #pragma unroll
      for (int dy = 0; dy < 5; ++dy) {
        const unsigned* rowp = &sHS[buf][ly + dy][0];
        const uint4 W0 = *(const uint4*)&swHS[dy][0];
        const uint4 W1 = *(const uint4*)&swHS[dy][4];
        const uint4 W2 = *(const uint4*)&swHS[dy][8];
        const uint4 W3 = *(const uint4*)&swHS[dy][12];
        const unsigned wt[15] = {W0.x, W0.y, W0.z, W0.w, W1.x, W1.y, W1.z, W1.w,
                                 W2.x, W2.y, W2.z, W2.w, W3.x, W3.y, W3.z};
        #pragma unroll
        for (int q = 0; q < 2; ++q) {
          const int base = c0 + 32 * q;
          const uint4 A0 = *(const uint4*)(rowp + base);
          const uint4 A1 = *(const uint4*)(rowp + base + 4);
          const unsigned hw[8] = {A0.x, A0.y, A0.z, A0.w, A1.x, A1.y, A1.z, A1.w};
          #pragma unroll
          for (int o = 0; o < 3; ++o)
            #pragma unroll
            for (int p = 0; p < 4; ++p)
              #pragma unroll
              for (int dx = 0; dx < 5; ++dx)
                acc[q][o][p] = fd2(hw[p + dx], wt[o * 5 + dx], acc[q][o][p]);
        }
      }
      #pragma unroll
      for (int o = 0; o < 3; ++o) {
        *(float4*)(outr + o * pln + ob)      = make_float4(acc[0][o][0], acc[0][o][1], acc[0][o][2], acc[0][o][3]);
        *(float4*)(outr + o * pln + ob + 32) = make_float4(acc[1][o][0], acc[1][o][1], acc[1][o][2], acc[1][o][3]);
      }
    }

    // pass 2: L -> xl  (two quads; f16 words 16q+2lx .. +4; alignbit odd px)
    {
      float acc[2][3][4];
      #pragma unroll
      for (int q = 0; q < 2; ++q)
        #pragma unroll
        for (int p = 0; p < 4; ++p) { acc[q][0][p] = b1v0; acc[q][1][p] = b1v1; acc[q][2][p] = b1v2; }
      #pragma unroll
      for (int dy = 0; dy < 5; ++dy) {
        const unsigned* rp = (const unsigned*)&sL[buf][ly + dy][0];
        const uint4 V0 = *(const uint4*)&swL[dy][0];
        const uint4 V1 = *(const uint4*)&swL[dy][4];
        const unsigned c8 = swL[dy][8];
        const unsigned wt[9] = {V0.x, V0.y, V0.z, V0.w, V1.x, V1.y, V1.z, V1.w, c8};
        #pragma unroll
        for (int q = 0; q < 2; ++q) {
          const int wb = 16 * q + 2 * lx;
          const uint2 Wa = *(const uint2*)(rp + wb);
          const uint2 Wb = *(const uint2*)(rp + wb + 2);
          const unsigned w4 = rp[wb + 4];
          const unsigned w[5] = {Wa.x, Wa.y, Wb.x, Wb.y, w4};
          unsigned s[4];
          #pragma unroll
          for (int k = 0; k < 4; ++k)
            s[k] = __builtin_amdgcn_alignbit(w[k + 1], w[k], 16);
          #pragma unroll
          for (int o = 0; o < 3; ++o)
            #pragma unroll
            for (int p = 0; p < 4; ++p) {
              const int hh = p >> 1;
              const unsigned* src = (p & 1) ? s : w;
              acc[q][o][p] = fd2(src[hh],     wt[o * 3 + 0], acc[q][o][p]);
              acc[q][o][p] = fd2(src[hh + 1], wt[o * 3 + 1], acc[q][o][p]);
              acc[q][o][p] = fd2(src[hh + 2], wt[o * 3 + 2], acc[q][o][p]);
            }
        }
      }
      #pragma unroll
      for (int o = 0; o < 3; ++o) {
        *(float4*)(outl + o * pln + ob)      = make_float4(acc[0][o][0], acc[0][o][1], acc[0][o][2], acc[0][o][3]);
        *(float4*)(outl + o * pln + ob + 32) = make_float4(acc[1][o][0], acc[1][o][1], acc[1][o][2], acc[1][o][3]);
      }
    }

    // stage next tile into the other buffer (precise vmcnt wait lands here)
    if (it + 1 < NT) {
      convert_store(buf ^ 1, Rn, Gn, Bn);
      wg_barrier_lds();
    }
  }
}

extern "C" void kernel_launch(void* const* d_in, const int* in_sizes, int n_in,
                              void* d_out, int out_size, void* d_ws, size_t ws_size,
                              hipStream_t stream) {
  const float* x  = (const float*)d_in[0];
  const float* w1 = (const float*)d_in[1];
  const float* b1 = (const float*)d_in[2];
  const float* w2 = (const float*)d_in[3];
  const float* b2 = (const float*)d_in[4];
  float* out = (float*)d_out;

  const int B = in_sizes[0] / (3 * 512 * 512);   // 32
  const int grid = B * 32;                       // 1024 blocks, 4 tiles each
  fused_hsl_conv<<<grid, 256, 0, stream>>>(x, w1, b1, w2, b2, out, B);
}

// Round 15
// 62.865 us; speedup vs baseline: 1.2213x; 1.2213x over previous
//
#include <hip/hip_runtime.h>

typedef _Float16 h2 __attribute__((ext_vector_type(2)));
typedef float f4 __attribute__((ext_vector_type(4)));

__device__ __forceinline__ float fd2(unsigned a, unsigned b, float c) {
  return __builtin_amdgcn_fdot2(__builtin_bit_cast(h2, a), __builtin_bit_cast(h2, b), c, false);
}
__device__ __forceinline__ unsigned pkrtz(float a, float b) {
  return __builtin_bit_cast(unsigned, __builtin_amdgcn_cvt_pkrtz(a, b));
}
__device__ __forceinline__ void nt_store4(float* p, float a, float b, float c, float d) {
  f4 v = {a, b, c, d};
  __builtin_nontemporal_store(v, (f4*)p);
}

// LDS-only barrier: drains ds ops, leaves global loads/stores in flight.
__device__ __forceinline__ void wg_barrier_lds() {
  asm volatile("s_waitcnt lgkmcnt(0)\n\ts_barrier" ::: "memory");
}

#define TW 64
#define TH 32
#define ROWS 36   // TH + 4
#define SWW 84    // sHS row stride (words)
#define SLW 88    // sL  row stride (f16s)
#define NT 4      // tiles (stacked in y) per block

__global__ __launch_bounds__(256, 4) void fused_hsl_conv(
    const float* __restrict__ x,
    const float* __restrict__ w1,
    const float* __restrict__ b1,
    const float* __restrict__ w2,
    const float* __restrict__ b2,
    float* __restrict__ out,
    int B)
{
  __shared__ unsigned sHS[2][ROWS][SWW];
  __shared__ __align__(16) _Float16 sL[2][ROWS][SLW];
  __shared__ unsigned swHS[5][16];
  __shared__ unsigned swL[5][16];

  const int tid = threadIdx.x;

  // ---- weight staging ----
  if (tid < 15) {
    const int o = tid % 3, dy = tid / 3;
    #pragma unroll
    for (int dx = 0; dx < 5; ++dx)
      swHS[dy][o * 5 + dx] = pkrtz(w2[o * 50 + dy * 5 + dx],
                                   w2[o * 50 + 25 + dy * 5 + dx]);
  } else if (tid >= 32 && tid < 47) {
    const int t2 = tid - 32, o = t2 % 3, dy = t2 / 3;
    float wv[5];
    #pragma unroll
    for (int dx = 0; dx < 5; ++dx) wv[dx] = w1[o * 25 + dy * 5 + dx];
    swL[dy][o * 3 + 0] = pkrtz(wv[0], wv[1]);
    swL[dy][o * 3 + 1] = pkrtz(wv[2], wv[3]);
    swL[dy][o * 3 + 2] = pkrtz(wv[4], 0.f);
  } else if (tid >= 64 && tid < 69) {
    swHS[tid - 64][15] = 0;
  } else if (tid >= 96 && tid < 131) {
    const int t3 = tid - 96;
    swL[t3 / 7][9 + t3 % 7] = 0;
  }
  // zero sL pad words 34,35 of every row, BOTH buffers
  if (tid < 72) {
    const int r = tid >> 1, w = 34 + (tid & 1);
    ((unsigned*)&sL[0][r][0])[w] = 0;
    ((unsigned*)&sL[1][r][0])[w] = 0;
  }

  // ---- block -> (b, tx, ychunk) with bijective XCD swizzle ----
  const int nwg = gridDim.x;                      // B*32, %8==0
  const int bsw = (blockIdx.x & 7) * (nwg >> 3) + (blockIdx.x >> 3);
  const int b   = bsw >> 5;
  const int rem = bsw & 31;
  const int tx0 = (rem & 7) * TW;
  const int tyb = (rem >> 3) * (NT * TH);

  const size_t pln = 512 * 512;
  const float* pr = x + (size_t)b * 3 * pln;
  const float* pg = pr + pln;
  const float* pb = pg + pln;
  float* outl = out + (size_t)b * 3 * pln;
  float* outr = out + ((size_t)B + b) * 3 * pln;

  const float b1v0 = b1[0], b1v1 = b1[1], b1v2 = b1[2];
  const float b2v0 = b2[0], b2v1 = b2[1], b2v2 = b2[2];

  // staging geometry: 36 rows x 18 float4-groups = 648 = 3*216
  const bool act = tid < 216;
  int rowA[3], tA[3];
  #pragma unroll
  for (int k = 0; k < 3; ++k) {
    const int i = k * 216 + tid;
    rowA[k] = i / 18;
    tA[k]   = i - rowA[k] * 18;
  }

  auto issue_loads = [&](int ty0, float4* Rv, float4* Gv, float4* Bv) {
    #pragma unroll
    for (int k = 0; k < 3; ++k) {
      const int gy  = ty0 - 2 + rowA[k];
      const int gx0 = tx0 - 4 + 4 * tA[k];
      Rv[k] = make_float4(0.f, 0.f, 0.f, 0.f);
      Gv[k] = Rv[k]; Bv[k] = Rv[k];
      if (act && gy >= 0 && gy < 512 && gx0 >= 0 && gx0 < 512) {
        const size_t off = (size_t)gy * 512 + gx0;
        Rv[k] = *(const float4*)(pr + off);
        Gv[k] = *(const float4*)(pg + off);
        Bv[k] = *(const float4*)(pb + off);
      }
    }
  };

  auto convert_store = [&](int buf, const float4* Rv, const float4* Gv, const float4* Bv) {
    #pragma unroll
    for (int k = 0; k < 3; ++k) {
      const int row = rowA[k], t = tA[k];
      const float ra[4] = {Rv[k].x, Rv[k].y, Rv[k].z, Rv[k].w};
      const float ga[4] = {Gv[k].x, Gv[k].y, Gv[k].z, Gv[k].w};
      const float ba[4] = {Bv[k].x, Bv[k].y, Bv[k].z, Bv[k].w};
      unsigned hs[4]; _Float16 lv[4];
      #pragma unroll
      for (int p = 0; p < 4; ++p) {
        const float r = ra[p], g = ga[p], bl = ba[p];
        const float cmax = fmaxf(r, fmaxf(g, bl));
        const float cmin = fminf(r, fminf(g, bl));
        const float delta = cmax - cmin;
        const float l = 0.5f * (cmax + cmin);
        const float rd = __builtin_amdgcn_rcpf(delta);
        float h0 = (g - bl) * rd;
        h0 = (h0 < 0.f) ? h0 + 6.f : h0;
        const float h1v = (bl - r) * rd + 2.f;
        const float h2v = (r - g) * rd + 4.f;
        float hv = (r >= g && r >= bl) ? h0 : ((g >= bl) ? h1v : h2v);
        const float h = (delta != 0.f) ? hv * (1.f / 6.f) : 0.f;
        const float denom = (l <= 0.5f) ? (2.f * l) : (2.f - 2.f * l);
        const float s = (delta != 0.f && l > 0.f && l < 1.f)
                          ? delta * __builtin_amdgcn_rcpf(denom) : 0.f;
        hs[p] = pkrtz(h, s);
        lv[p] = (_Float16)l;
      }
      if (act) {
        if (t >= 1)  *(uint2*)&sHS[buf][row][4 * t - 2] = make_uint2(hs[0], hs[1]);
        if (t <= 16) *(uint2*)&sHS[buf][row][4 * t]     = make_uint2(hs[2], hs[3]);
        unsigned* rl = (unsigned*)&sL[buf][row][0];
        if (t >= 1)  rl[2 * t - 1] = __builtin_bit_cast(unsigned, (h2){lv[0], lv[1]});
        if (t <= 16) rl[2 * t]     = __builtin_bit_cast(unsigned, (h2){lv[2], lv[3]});
      }
    }
  };

  // conv ownership: lane owns TWO quads of one row: px 4lx..4lx+3 and 32+4lx..35+4lx.
  const int lx = tid & 7;      // 0..7
  const int ly = tid >> 3;     // 0..31
  const int c0 = 4 * lx;       // quad A px base; quad B = c0 + 32

  // ---- prologue: tile 0 ----
  float4 Rv[3], Gv[3], Bv[3];
  issue_loads(tyb, Rv, Gv, Bv);
  convert_store(0, Rv, Gv, Bv);
  wg_barrier_lds();

  for (int it = 0; it < NT; ++it) {
    const int ty0 = tyb + it * TH;
    const int buf = it & 1;

    // issue next tile's loads; pin above compute
    float4 Rn[3], Gn[3], Bn[3];
    if (it + 1 < NT) issue_loads(ty0 + TH, Rn, Gn, Bn);
    __builtin_amdgcn_sched_barrier(0);

    const size_t ob = (size_t)(ty0 + ly) * 512 + (tx0 + c0);

    // pass 1: HS -> xr  (two quads; tap dx of px p uses word base+p+dx)
    {
      float acc[2][3][4];
      #pragma unroll
      for (int q = 0; q < 2; ++q)
        #pragma unroll
        for (int p = 0; p < 4; ++p) { acc[q][0][p] = b2v0; acc[q][1][p] = b2v1; acc[q][2][p] = b2v2; }
      #pragma unroll
      for (int dy = 0; dy < 5; ++dy) {
        const unsigned* rowp = &sHS[buf][ly + dy][0];
        const uint4 W0 = *(const uint4*)&swHS[dy][0];
        const uint4 W1 = *(const uint4*)&swHS[dy][4];
        const uint4 W2 = *(const uint4*)&swHS[dy][8];
        const uint4 W3 = *(const uint4*)&swHS[dy][12];
        const unsigned wt[15] = {W0.x, W0.y, W0.z, W0.w, W1.x, W1.y, W1.z, W1.w,
                                 W2.x, W2.y, W2.z, W2.w, W3.x, W3.y, W3.z};
        #pragma unroll
        for (int q = 0; q < 2; ++q) {
          const int base = c0 + 32 * q;
          const uint4 A0 = *(const uint4*)(rowp + base);
          const uint4 A1 = *(const uint4*)(rowp + base + 4);
          const unsigned hw[8] = {A0.x, A0.y, A0.z, A0.w, A1.x, A1.y, A1.z, A1.w};
          #pragma unroll
          for (int o = 0; o < 3; ++o)
            #pragma unroll
            for (int p = 0; p < 4; ++p)
              #pragma unroll
              for (int dx = 0; dx < 5; ++dx)
                acc[q][o][p] = fd2(hw[p + dx], wt[o * 5 + dx], acc[q][o][p]);
        }
      }
      // Non-temporal: outputs are never re-read; bypass L2 write-allocate so
      // the halo rows we re-read next iteration stay resident.
      #pragma unroll
      for (int o = 0; o < 3; ++o) {
        nt_store4(outr + o * pln + ob,      acc[0][o][0], acc[0][o][1], acc[0][o][2], acc[0][o][3]);
        nt_store4(outr + o * pln + ob + 32, acc[1][o][0], acc[1][o][1], acc[1][o][2], acc[1][o][3]);
      }
    }

    // pass 2: L -> xl  (two quads; f16 words 16q+2lx .. +4; alignbit odd px)
    {
      float acc[2][3][4];
      #pragma unroll
      for (int q = 0; q < 2; ++q)
        #pragma unroll
        for (int p = 0; p < 4; ++p) { acc[q][0][p] = b1v0; acc[q][1][p] = b1v1; acc[q][2][p] = b1v2; }
      #pragma unroll
      for (int dy = 0; dy < 5; ++dy) {
        const unsigned* rp = (const unsigned*)&sL[buf][ly + dy][0];
        const uint4 V0 = *(const uint4*)&swL[dy][0];
        const uint4 V1 = *(const uint4*)&swL[dy][4];
        const unsigned c8 = swL[dy][8];
        const unsigned wt[9] = {V0.x, V0.y, V0.z, V0.w, V1.x, V1.y, V1.z, V1.w, c8};
        #pragma unroll
        for (int q = 0; q < 2; ++q) {
          const int wb = 16 * q + 2 * lx;
          const uint2 Wa = *(const uint2*)(rp + wb);
          const uint2 Wb = *(const uint2*)(rp + wb + 2);
          const unsigned w4 = rp[wb + 4];
          const unsigned w[5] = {Wa.x, Wa.y, Wb.x, Wb.y, w4};
          unsigned s[4];
          #pragma unroll
          for (int k = 0; k < 4; ++k)
            s[k] = __builtin_amdgcn_alignbit(w[k + 1], w[k], 16);
          #pragma unroll
          for (int o = 0; o < 3; ++o)
            #pragma unroll
            for (int p = 0; p < 4; ++p) {
              const int hh = p >> 1;
              const unsigned* src = (p & 1) ? s : w;
              acc[q][o][p] = fd2(src[hh],     wt[o * 3 + 0], acc[q][o][p]);
              acc[q][o][p] = fd2(src[hh + 1], wt[o * 3 + 1], acc[q][o][p]);
              acc[q][o][p] = fd2(src[hh + 2], wt[o * 3 + 2], acc[q][o][p]);
            }
        }
      }
      #pragma unroll
      for (int o = 0; o < 3; ++o) {
        nt_store4(outl + o * pln + ob,      acc[0][o][0], acc[0][o][1], acc[0][o][2], acc[0][o][3]);
        nt_store4(outl + o * pln + ob + 32, acc[1][o][0], acc[1][o][1], acc[1][o][2], acc[1][o][3]);
      }
    }

    // stage next tile into the other buffer (precise vmcnt wait lands here)
    if (it + 1 < NT) {
      convert_store(buf ^ 1, Rn, Gn, Bn);
      wg_barrier_lds();
    }
  }
}

extern "C" void kernel_launch(void* const* d_in, const int* in_sizes, int n_in,
                              void* d_out, int out_size, void* d_ws, size_t ws_size,
                              hipStream_t stream) {
  const float* x  = (const float*)d_in[0];
  const float* w1 = (const float*)d_in[1];
  const float* b1 = (const float*)d_in[2];
  const float* w2 = (const float*)d_in[3];
  const float* b2 = (const float*)d_in[4];
  float* out = (float*)d_out;

  const int B = in_sizes[0] / (3 * 512 * 512);   // 32
  const int grid = B * 32;                       // 1024 blocks, 4 tiles each
  fused_hsl_conv<<<grid, 256, 0, stream>>>(x, w1, b1, w2, b2, out, B);
}